// Round 1
// baseline (53054.559 us; speedup 1.0000x reference)
//
#include <hip/hip_runtime.h>

#define NB    256   // grid blocks (== 1 per CU, all co-resident)
#define BT    256   // threads per block
#define BATCH 128
#define HID   512
#define XSZ   64
#define SSZ   16

// ---------------- persistent device state (re-initialized every launch) ----------------
__device__ __align__(16) float g_h0T[2][HID * BATCH];  // transposed h0, double buffered
__device__ __align__(16) float g_h1T[2][HID * BATCH];  // transposed h1, double buffered
__device__ __align__(16) float g_sT[SSZ * BATCH];      // transposed s
__device__ int g_flags[NB];
__device__ int g_gen;

// ---------------- math helpers ----------------
__device__ __forceinline__ float sigf(float x) { return 1.f / (1.f + __expf(-x)); }
__device__ __forceinline__ float tanh_fast(float x) {
  float ax = fabsf(x);
  float e  = __expf(-2.f * ax);
  float r  = (1.f - e) / (1.f + e);
  return copysignf(r, x);
}

// ---------------- grid barrier (flag array + generation, agent scope) ----------------
__device__ __forceinline__ void grid_barrier(int bk, int tid, int pid) {
  __syncthreads();
  __threadfence();  // release: make this block's global writes visible device-wide
  if (bk == 0) {
    if (tid > 0 && tid < NB) {
      while (__hip_atomic_load(&g_flags[tid], __ATOMIC_RELAXED, __HIP_MEMORY_SCOPE_AGENT) < pid)
        __builtin_amdgcn_s_sleep(1);
    }
    __syncthreads();
    if (tid == 0)
      __hip_atomic_store(&g_gen, pid, __ATOMIC_RELEASE, __HIP_MEMORY_SCOPE_AGENT);
  } else {
    if (tid == 0) {
      __hip_atomic_store(&g_flags[bk], pid, __ATOMIC_RELEASE, __HIP_MEMORY_SCOPE_AGENT);
      while (__hip_atomic_load(&g_gen, __ATOMIC_ACQUIRE, __HIP_MEMORY_SCOPE_AGENT) < pid)
        __builtin_amdgcn_s_sleep(1);
    }
    __syncthreads();
  }
  __threadfence();  // acquire: ensure subsequent reads see all blocks' writes
}

// ---------------- setup: zero state, transpose s0, cal_times, barrier init ----------------
__global__ void setup_kernel(const float* __restrict__ s0, float* __restrict__ out, int T) {
  int idx = blockIdx.x * blockDim.x + threadIdx.x;
  int n   = gridDim.x * blockDim.x;
  for (int i = idx; i < HID * BATCH; i += n) {
    g_h0T[0][i] = 0.f; g_h0T[1][i] = 0.f;
    g_h1T[0][i] = 0.f; g_h1T[1][i] = 0.f;
  }
  for (int i = idx; i < BATCH * SSZ; i += n) {
    int b = i >> 4, j = i & 15;
    g_sT[j * BATCH + b] = s0[i];
  }
  for (int t = idx; t < T; t += n) out[BATCH * T * SSZ + t] = (float)t * 0.1f;
  for (int i = idx; i < NB; i += n) g_flags[i] = 0;
  if (idx == 0) g_gen = 0;
}

// ---------------- persistent RNN kernel ----------------
__global__ __launch_bounds__(BT) void persist_kernel(
    const float* __restrict__ x,
    const float* __restrict__ Wih0, const float* __restrict__ Whh0,
    const float* __restrict__ bih0, const float* __restrict__ bhh0,
    const float* __restrict__ Wih1, const float* __restrict__ Whh1,
    const float* __restrict__ bih1, const float* __restrict__ bhh1,
    const float* __restrict__ Wfc,  const float* __restrict__ bfc,
    float* __restrict__ out, int T)
{
  __shared__ float gbuf[8][BATCH];   // preactivation exchange (8 gate-rows x 128 batch)
  __shared__ float c0s[2][BATCH];    // this block's c0 columns
  __shared__ float c1s[2][BATCH];    // this block's c1 columns
  __shared__ float cbuf[2][BATCH];   // fc partial sums

  const int bk  = blockIdx.x;
  const int tid = threadIdx.x;
  const int r8  = tid >> 5;   // 0..7 : which of the 8 gate-rows this thread computes
  const int bq  = tid & 31;   // batch quad: owns batch rows 4bq..4bq+3
  const int gi  = r8 >> 1;    // gate index 0..3 (i,f,g,o)
  const int jj  = r8 & 1;     // which of the block's 2 hidden columns
  const int j0  = bk * 2;
  const int row = gi * HID + j0 + jj;   // row into the [2048 x K] weight matrices

  if (tid < 2 * BATCH) {
    c0s[tid >> 7][tid & 127] = 0.f;
    c1s[tid >> 7][tid & 127] = 0.f;
  }
  __syncthreads();

  // ---- precompute: biases + x-contribution (x is constant over time) ----
  float base0, base1, base2, base3;
  {
    const float bb = bih0[row] + bhh0[row];
    const float* wr = Wih0 + row * (XSZ + SSZ);
    const float* x0 = x + (bq * 4 + 0) * XSZ;
    const float* x1 = x + (bq * 4 + 1) * XSZ;
    const float* x2 = x + (bq * 4 + 2) * XSZ;
    const float* x3 = x + (bq * 4 + 3) * XSZ;
    float a0 = bb, a1 = bb, a2 = bb, a3 = bb;
#pragma unroll 4
    for (int k = 0; k < XSZ; k++) {
      float w = wr[k];
      a0 += w * x0[k]; a1 += w * x1[k]; a2 += w * x2[k]; a3 += w * x3[k];
    }
    base0 = a0; base1 = a1; base2 = a2; base3 = a3;
  }
  const float bias1 = bih1[row] + bhh1[row];

  const float* w0s = Wih0 + row * (XSZ + SSZ) + XSZ;  // s-part of layer-0 input weights
  const float* w0h = Whh0 + row * HID;
  const float* w1a = Wih1 + row * HID;
  const float* w1b = Whh1 + row * HID;

  int p = 0;
  int pid = 0;

  for (int t = 0; t < T; ++t) {
    // ================= phase A : layer-0 gates + h0/c0 update =================
    {
      float a0 = base0, a1 = base1, a2 = base2, a3 = base3;
      const float4* sT = (const float4*)g_sT;           // [16][32] of float4
#pragma unroll
      for (int k = 0; k < SSZ; k++) {
        float w = w0s[k];
        float4 v = sT[k * 32 + bq];
        a0 += w * v.x; a1 += w * v.y; a2 += w * v.z; a3 += w * v.w;
      }
      const float4* hT = (const float4*)g_h0T[p];       // [512][32] of float4
#pragma unroll 4
      for (int k = 0; k < HID; k++) {
        float w = w0h[k];
        float4 v = hT[k * 32 + bq];
        a0 += w * v.x; a1 += w * v.y; a2 += w * v.z; a3 += w * v.w;
      }
      float* gr = &gbuf[r8][bq * 4];
      gr[0] = a0; gr[1] = a1; gr[2] = a2; gr[3] = a3;
    }
    __syncthreads();
    {
      const int j2 = tid >> 7, b = tid & 127;
      float vi = gbuf[0 + j2][b];
      float vf = gbuf[2 + j2][b];
      float vg = gbuf[4 + j2][b];
      float vo = gbuf[6 + j2][b];
      float c  = c0s[j2][b];
      c = sigf(vf) * c + sigf(vi) * tanh_fast(vg);
      c0s[j2][b] = c;
      g_h0T[p ^ 1][(j0 + j2) * BATCH + b] = sigf(vo) * tanh_fast(c);
    }
    ++pid; grid_barrier(bk, tid, pid);

    // ================= phase B : layer-1 gates + h1/c1 update =================
    {
      float a0 = bias1, a1 = bias1, a2 = bias1, a3 = bias1;
      const float4* hT = (const float4*)g_h0T[p ^ 1];   // new h0
#pragma unroll 4
      for (int k = 0; k < HID; k++) {
        float w = w1a[k];
        float4 v = hT[k * 32 + bq];
        a0 += w * v.x; a1 += w * v.y; a2 += w * v.z; a3 += w * v.w;
      }
      const float4* h1T = (const float4*)g_h1T[p];      // previous h1
#pragma unroll 4
      for (int k = 0; k < HID; k++) {
        float w = w1b[k];
        float4 v = h1T[k * 32 + bq];
        a0 += w * v.x; a1 += w * v.y; a2 += w * v.z; a3 += w * v.w;
      }
      float* gr = &gbuf[r8][bq * 4];
      gr[0] = a0; gr[1] = a1; gr[2] = a2; gr[3] = a3;
    }
    __syncthreads();
    {
      const int j2 = tid >> 7, b = tid & 127;
      float vi = gbuf[0 + j2][b];
      float vf = gbuf[2 + j2][b];
      float vg = gbuf[4 + j2][b];
      float vo = gbuf[6 + j2][b];
      float c  = c1s[j2][b];
      c = sigf(vf) * c + sigf(vi) * tanh_fast(vg);
      c1s[j2][b] = c;
      g_h1T[p ^ 1][(j0 + j2) * BATCH + b] = sigf(vo) * tanh_fast(c);
    }
    ++pid; grid_barrier(bk, tid, pid);

    // ================= phase C : fc + Euler update of s (blocks 0..15) =================
    if (bk < SSZ) {
      const int b = tid & 127, half = tid >> 7;
      const float* wf = Wfc + bk * HID + half * 256;
      const float* hp = g_h1T[p ^ 1] + half * 256 * BATCH + b;
      float acc = 0.f;
#pragma unroll 8
      for (int k = 0; k < 256; k++) acc += wf[k] * hp[k * BATCH];
      cbuf[half][b] = acc;
      __syncthreads();
      if (tid < BATCH) {
        float so = bfc[bk] + cbuf[0][tid] + cbuf[1][tid];
        float sn = g_sT[bk * BATCH + tid] + 0.1f * so;
        g_sT[bk * BATCH + tid] = sn;
        out[tid * (T * SSZ) + t * SSZ + bk] = sn;                          // outputs
        out[BATCH * T * SSZ + T + tid * (T * SSZ) + t * SSZ + bk] = so;    // res_steps
      }
    }
    ++pid; grid_barrier(bk, tid, pid);

    p ^= 1;
  }
}

extern "C" void kernel_launch(void* const* d_in, const int* in_sizes, int n_in,
                              void* d_out, int out_size, void* d_ws, size_t ws_size,
                              hipStream_t stream) {
  const float* x    = (const float*)d_in[0];
  const float* s0   = (const float*)d_in[1];
  const float* Wih0 = (const float*)d_in[2];
  const float* Whh0 = (const float*)d_in[3];
  const float* bih0 = (const float*)d_in[4];
  const float* bhh0 = (const float*)d_in[5];
  const float* Wih1 = (const float*)d_in[6];
  const float* Whh1 = (const float*)d_in[7];
  const float* bih1 = (const float*)d_in[8];
  const float* bhh1 = (const float*)d_in[9];
  const float* Wfc  = (const float*)d_in[10];
  const float* bfc  = (const float*)d_in[11];
  float* out = (float*)d_out;

  const int T = out_size / (2 * BATCH * SSZ + 1);  // outputs + cal_times + res_steps

  setup_kernel<<<64, 256, 0, stream>>>(s0, out, T);
  persist_kernel<<<NB, BT, 0, stream>>>(x, Wih0, Whh0, bih0, bhh0,
                                        Wih1, Whh1, bih1, bhh1, Wfc, bfc, out, T);
}

// Round 3
// 23430.972 us; speedup vs baseline: 2.2643x; 2.2643x over previous
//
#include <hip/hip_runtime.h>

#define NB    256   // compute blocks (1/CU); block NB is the barrier master
#define BT    512   // threads per block (8 waves = 2 per SIMD)
#define BATCH 128
#define HID   512
#define XSZ   64
#define SSZ   16
#define PAD   32    // ints per flag slot = 128B line
#define SPIN_MAX (1 << 20)   // safety valve: degrade to wrong-fast instead of hang

// ---------------- persistent device state (re-initialized every launch) ----------------
__device__ __align__(16) float g_h0T[2][HID * BATCH];   // transposed h0, double buffered
__device__ __align__(16) float g_h1T[2][HID * BATCH];   // transposed h1, double buffered
__device__ __align__(16) float g_h1N[BATCH * HID];      // row-major h1 copy for fc
__device__ __align__(16) float g_Wcomb[4 * HID * HID];  // 0.1 * W0s @ Wfc   [2048][512]
__device__ int g_arrive[NB * PAD];                      // one 128B line per block
__device__ int g_release[NB * PAD];

// ---------------- math helpers ----------------
__device__ __forceinline__ float sigf(float x) { return 1.f / (1.f + __expf(-x)); }
__device__ __forceinline__ float tanh_fast(float x) {
  float ax = fabsf(x);
  float e  = __expf(-2.f * ax);
  float r  = (1.f - e) / (1.f + e);
  return copysignf(r, x);
}

// wave polls its own block's release line (one line, one load/wave) then acquires
__device__ __forceinline__ void wait_release(int bk, int pid) {
  int guard = 0;
  while (__hip_atomic_load(&g_release[bk * PAD], __ATOMIC_RELAXED, __HIP_MEMORY_SCOPE_AGENT) < pid) {
    __builtin_amdgcn_s_sleep(2);
    if (++guard > SPIN_MAX) break;   // pathological: give up, finish with garbage
  }
  __threadfence();  // acquire side
}

// 4-batch GEMV slice: acc += w_row[0:512] . actT[0:512][bq*4..bq*4+3]
__device__ __forceinline__ void dot4(const float* __restrict__ w,
                                     const float* __restrict__ actT, int bq,
                                     float& a0, float& a1, float& a2, float& a3) {
  const float4* __restrict__ w4 = (const float4*)w;
  const float4* __restrict__ v4 = (const float4*)actT;
#pragma unroll 2
  for (int k4 = 0; k4 < HID / 4; ++k4) {
    float4 w_ = w4[k4];
    float4 v0 = v4[(k4 * 4 + 0) * 32 + bq];
    float4 v1 = v4[(k4 * 4 + 1) * 32 + bq];
    float4 v2 = v4[(k4 * 4 + 2) * 32 + bq];
    float4 v3 = v4[(k4 * 4 + 3) * 32 + bq];
    a0 += w_.x * v0.x; a1 += w_.x * v0.y; a2 += w_.x * v0.z; a3 += w_.x * v0.w;
    a0 += w_.y * v1.x; a1 += w_.y * v1.y; a2 += w_.y * v1.z; a3 += w_.y * v1.w;
    a0 += w_.z * v2.x; a1 += w_.z * v2.y; a2 += w_.z * v2.z; a3 += w_.z * v2.w;
    a0 += w_.w * v3.x; a1 += w_.w * v3.y; a2 += w_.w * v3.z; a3 += w_.w * v3.w;
  }
}

// ---------------- setup: zero state, cal_times, flags ----------------
__global__ void setup_kernel(float* __restrict__ out, int T) {
  int idx = blockIdx.x * blockDim.x + threadIdx.x;
  int n   = gridDim.x * blockDim.x;
  for (int i = idx; i < HID * BATCH; i += n) {
    g_h0T[0][i] = 0.f; g_h0T[1][i] = 0.f;
    g_h1T[0][i] = 0.f; g_h1T[1][i] = 0.f;
  }
  for (int t = idx; t < T; t += n) out[BATCH * T * SSZ + t] = (float)t * 0.1f;
  for (int i = idx; i < NB * PAD; i += n) { g_arrive[i] = 0; g_release[i] = 0; }
}

// ---------------- Wcomb = 0.1 * W0s @ Wfc ----------------
__global__ void wcomb_kernel(const float* __restrict__ Wih0, const float* __restrict__ Wfc) {
  int idx = blockIdx.x * blockDim.x + threadIdx.x;  // 2048*512 threads
  int row = idx >> 9, k = idx & (HID - 1);
  float a = 0.f;
#pragma unroll
  for (int m = 0; m < SSZ; m++) a += Wih0[row * (XSZ + SSZ) + XSZ + m] * Wfc[m * HID + k];
  g_Wcomb[idx] = 0.1f * a;
}

// ---------------- persistent RNN kernel ----------------
__global__ __launch_bounds__(BT, 4) void persist_kernel(
    const float* __restrict__ x,    const float* __restrict__ s0,
    const float* __restrict__ Wih0, const float* __restrict__ Whh0,
    const float* __restrict__ bih0, const float* __restrict__ bhh0,
    const float* __restrict__ Wih1, const float* __restrict__ Whh1,
    const float* __restrict__ bih1, const float* __restrict__ bhh1,
    const float* __restrict__ Wfc,  const float* __restrict__ bfc,
    float* __restrict__ out, int T)
{
  const int bk  = blockIdx.x;
  const int tid = threadIdx.x;

  // ============ barrier master block ============
  if (bk == NB) {
    for (int pid = 1; pid <= 2 * T; ++pid) {
      if (tid < NB) {
        int guard = 0;
        while (__hip_atomic_load(&g_arrive[tid * PAD], __ATOMIC_RELAXED, __HIP_MEMORY_SCOPE_AGENT) < pid) {
          __builtin_amdgcn_s_sleep(2);
          if (++guard > SPIN_MAX) break;
        }
      }
      __syncthreads();
      __threadfence();
      if (tid < NB)
        __hip_atomic_store(&g_release[tid * PAD], pid, __ATOMIC_RELAXED, __HIP_MEMORY_SCOPE_AGENT);
    }
    return;
  }

  // ============ compute blocks ============
  __shared__ float gbuf[2][8][BATCH];  // [half][gate-row][batch] partials
  __shared__ float c0s[2][BATCH];
  __shared__ float c1s[2][BATCH];

  const int half = tid >> 8;     // 0: h0-K half, 1: h1-K half
  const int ht   = tid & 255;
  const int rid  = ht >> 5;      // 0..7 gate-row within block
  const int bq   = ht & 31;      // batch quad
  const int gi   = rid >> 1;     // gate 0..3 (i,f,g,o)
  const int jj   = rid & 1;
  const int j0   = bk * 2;
  const int row  = gi * HID + j0 + jj;

  if (tid < 2 * BATCH) {
    c0s[tid >> 7][tid & 127] = 0.f;
    c1s[tid >> 7][tid & 127] = 0.f;
  }
  __syncthreads();

  // ---- per-half init ----
  float base0 = 0, base1 = 0, base2 = 0, base3 = 0;  // half0: x.W + biases; half1: u_t
  float uconst = 0, bias1 = 0;
  if (half == 0) {
    const float bb = bih0[row] + bhh0[row];
    const float* wr = Wih0 + row * (XSZ + SSZ);
    float a0 = bb, a1 = bb, a2 = bb, a3 = bb;
#pragma unroll 4
    for (int k = 0; k < XSZ; k++) {
      float w = wr[k];
      a0 += w * x[(bq * 4 + 0) * XSZ + k];
      a1 += w * x[(bq * 4 + 1) * XSZ + k];
      a2 += w * x[(bq * 4 + 2) * XSZ + k];
      a3 += w * x[(bq * 4 + 3) * XSZ + k];
    }
    base0 = a0; base1 = a1; base2 = a2; base3 = a3;
    bias1 = bih1[row] + bhh1[row];
  } else {
    // u_0 = W0s.s0 ; uconst = 0.1 * W0s.bfc ; store u - uconst so loop adds uconst uniformly
    const float* ws = Wih0 + row * (XSZ + SSZ) + XSZ;
    float a0 = 0, a1 = 0, a2 = 0, a3 = 0, uc = 0;
#pragma unroll
    for (int m = 0; m < SSZ; m++) {
      float w = ws[m];
      uc += w * bfc[m];
      a0 += w * s0[(bq * 4 + 0) * SSZ + m];
      a1 += w * s0[(bq * 4 + 1) * SSZ + m];
      a2 += w * s0[(bq * 4 + 2) * SSZ + m];
      a3 += w * s0[(bq * 4 + 3) * SSZ + m];
    }
    uconst = 0.1f * uc;
    base0 = a0 - uconst; base1 = a1 - uconst; base2 = a2 - uconst; base3 = a3 - uconst;
  }

  // ---- fc/output lane state (wave 7 of blocks 128..255; one batch row each) ----
  const bool fc_wave = (bk >= 128) && (tid >= 448);
  const int  fb   = bk - 128;          // batch row owned
  const int  lane = tid & 63;
  float s_reg = 0.f, bfcj = 0.f;
  if (fc_wave) {
    if (lane < SSZ) { s_reg = s0[fb * SSZ + lane]; bfcj = bfc[lane]; }
  }

  const float* w0h = Whh0 + row * HID;
  const float* wcb = g_Wcomb + row * HID;
  const float* w1a = Wih1 + row * HID;
  const float* w1b = Whh1 + row * HID;

  int p = 0;
  for (int t = 0; t < T; ++t) {
    // ---------- phase A: gates0 ----------
    if (half == 1) {
      if (t > 0) wait_release(bk, 2 * t);   // h1_{t-1}, h1N fresh after barrier2 of t-1
      if (fc_wave && t > 0) {
        // fc for step t-1: so = Wfc.h1_{t-1} + bfc ; s += 0.1*so ; write outputs
        const float4* wf4 = (const float4*)(Wfc + (lane & 15) * HID + (lane >> 4) * 128);
        const float4* hv4 = (const float4*)(g_h1N + fb * HID + (lane >> 4) * 128);
        float acc = 0.f;
#pragma unroll
        for (int q = 0; q < 32; ++q) {
          float4 w = wf4[q], v = hv4[q];
          acc += w.x * v.x + w.y * v.y + w.z * v.z + w.w * v.w;
        }
        acc += __shfl_xor(acc, 16);
        acc += __shfl_xor(acc, 32);
        if (lane < SSZ) {
          float so = acc + bfcj;
          s_reg += 0.1f * so;
          out[fb * (T * SSZ) + (t - 1) * SSZ + lane] = s_reg;
          out[BATCH * T * SSZ + T + fb * (T * SSZ) + (t - 1) * SSZ + lane] = so;
        }
      }
      // u_t = u_{t-1} + Wcomb.h1_{t-1} + uconst
      float a0 = base0 + uconst, a1 = base1 + uconst, a2 = base2 + uconst, a3 = base3 + uconst;
      dot4(wcb, g_h1T[p], bq, a0, a1, a2, a3);
      base0 = a0; base1 = a1; base2 = a2; base3 = a3;  // carry u
      float* gr = &gbuf[1][rid][bq * 4];
      gr[0] = a0; gr[1] = a1; gr[2] = a2; gr[3] = a3;
    } else {
      float a0 = base0, a1 = base1, a2 = base2, a3 = base3;
      dot4(w0h, g_h0T[p], bq, a0, a1, a2, a3);   // warm (read last step's buffer)
      float* gr = &gbuf[0][rid][bq * 4];
      gr[0] = a0; gr[1] = a1; gr[2] = a2; gr[3] = a3;
    }
    __syncthreads();
    // ---------- activation A ----------
    if (tid < 256) {
      const int j2 = tid >> 7, b = tid & 127;
      float vi = gbuf[0][0 + j2][b] + gbuf[1][0 + j2][b];
      float vf = gbuf[0][2 + j2][b] + gbuf[1][2 + j2][b];
      float vg = gbuf[0][4 + j2][b] + gbuf[1][4 + j2][b];
      float vo = gbuf[0][6 + j2][b] + gbuf[1][6 + j2][b];
      float c  = c0s[j2][b];
      c = sigf(vf) * c + sigf(vi) * tanh_fast(vg);
      c0s[j2][b] = c;
      g_h0T[p ^ 1][(j0 + j2) * BATCH + b] = sigf(vo) * tanh_fast(c);
    }
    __syncthreads();
    if (tid == 0) {
      __threadfence();
      __hip_atomic_store(&g_arrive[bk * PAD], 2 * t + 1, __ATOMIC_RELAXED, __HIP_MEMORY_SCOPE_AGENT);
    }

    // ---------- phase B: gates1 ----------
    if (half == 1) {
      // warm path: W1b.h1_{t-1} — no barrier needed
      float a0 = 0, a1 = 0, a2 = 0, a3 = 0;
      dot4(w1b, g_h1T[p], bq, a0, a1, a2, a3);
      float* gr = &gbuf[1][rid][bq * 4];
      gr[0] = a0; gr[1] = a1; gr[2] = a2; gr[3] = a3;
    } else {
      wait_release(bk, 2 * t + 1);            // h0_t fresh
      float a0 = bias1, a1 = bias1, a2 = bias1, a3 = bias1;
      dot4(w1a, g_h0T[p ^ 1], bq, a0, a1, a2, a3);
      float* gr = &gbuf[0][rid][bq * 4];
      gr[0] = a0; gr[1] = a1; gr[2] = a2; gr[3] = a3;
    }
    __syncthreads();
    // ---------- activation B ----------
    if (tid < 256) {
      const int j2 = tid >> 7, b = tid & 127;
      float vi = gbuf[0][0 + j2][b] + gbuf[1][0 + j2][b];
      float vf = gbuf[0][2 + j2][b] + gbuf[1][2 + j2][b];
      float vg = gbuf[0][4 + j2][b] + gbuf[1][4 + j2][b];
      float vo = gbuf[0][6 + j2][b] + gbuf[1][6 + j2][b];
      float c  = c1s[j2][b];
      c = sigf(vf) * c + sigf(vi) * tanh_fast(vg);
      c1s[j2][b] = c;
      float h = sigf(vo) * tanh_fast(c);
      g_h1T[p ^ 1][(j0 + j2) * BATCH + b] = h;
      g_h1N[b * HID + j0 + j2] = h;
    }
    __syncthreads();
    if (tid == 0) {
      __threadfence();
      __hip_atomic_store(&g_arrive[bk * PAD], 2 * t + 2, __ATOMIC_RELAXED, __HIP_MEMORY_SCOPE_AGENT);
    }
    p ^= 1;
  }

  // ---------- final fc for step T-1 ----------
  if (fc_wave) {
    wait_release(bk, 2 * T);
    const float4* wf4 = (const float4*)(Wfc + (lane & 15) * HID + (lane >> 4) * 128);
    const float4* hv4 = (const float4*)(g_h1N + fb * HID + (lane >> 4) * 128);
    float acc = 0.f;
#pragma unroll
    for (int q = 0; q < 32; ++q) {
      float4 w = wf4[q], v = hv4[q];
      acc += w.x * v.x + w.y * v.y + w.z * v.z + w.w * v.w;
    }
    acc += __shfl_xor(acc, 16);
    acc += __shfl_xor(acc, 32);
    if (lane < SSZ) {
      float so = acc + bfcj;
      s_reg += 0.1f * so;
      out[fb * (T * SSZ) + (T - 1) * SSZ + lane] = s_reg;
      out[BATCH * T * SSZ + T + fb * (T * SSZ) + (T - 1) * SSZ + lane] = so;
    }
  }
}

extern "C" void kernel_launch(void* const* d_in, const int* in_sizes, int n_in,
                              void* d_out, int out_size, void* d_ws, size_t ws_size,
                              hipStream_t stream) {
  const float* x    = (const float*)d_in[0];
  const float* s0   = (const float*)d_in[1];
  const float* Wih0 = (const float*)d_in[2];
  const float* Whh0 = (const float*)d_in[3];
  const float* bih0 = (const float*)d_in[4];
  const float* bhh0 = (const float*)d_in[5];
  const float* Wih1 = (const float*)d_in[6];
  const float* Whh1 = (const float*)d_in[7];
  const float* bih1 = (const float*)d_in[8];
  const float* bhh1 = (const float*)d_in[9];
  const float* Wfc  = (const float*)d_in[10];
  const float* bfc  = (const float*)d_in[11];
  float* out = (float*)d_out;

  const int T = out_size / (2 * BATCH * SSZ + 1);

  setup_kernel<<<64, 256, 0, stream>>>(out, T);
  wcomb_kernel<<<(4 * HID * HID) / 256, 256, 0, stream>>>(Wih0, Wfc);
  persist_kernel<<<NB + 1, BT, 0, stream>>>(x, s0, Wih0, Whh0, bih0, bhh0,
                                            Wih1, Whh1, bih1, bhh1, Wfc, bfc, out, T);
}